// Round 2
// baseline (752.079 us; speedup 1.0000x reference)
//
#include <hip/hip_runtime.h>

#define BTOT 131072
#define TSEQ 15
#define BM   32

typedef __attribute__((ext_vector_type(8))) short bf16x8;
typedef __attribute__((ext_vector_type(4))) float f32x4;

__device__ __forceinline__ short f2bf(float f){
  union{float f; unsigned u;} v; v.f=f;
  unsigned r = v.u + 0x7FFFu + ((v.u>>16)&1u);
  return (short)(r>>16);
}

// Shared-rcp LSTM activation: 7 trans ops (5 exp2 + 2 rcp) instead of 10.
//  sf = 1/Df, si*tanh(g) = (eg-1)*Df / (Df*Di*Dg), h = (ec-1)/(Do*Dc)
__device__ __forceinline__ void lstm_act(float gi, float gf, float gg, float go,
                                         float& c, float& h){
  const float NL2E = -1.4426950408889634f;   // -log2(e)
  const float P2L2E = 2.8853900817779268f;   // 2*log2(e)
  float ef = __builtin_amdgcn_exp2f(gf * NL2E);
  float ei = __builtin_amdgcn_exp2f(gi * NL2E);
  float eg = __builtin_amdgcn_exp2f(gg * P2L2E);
  float Df = 1.f + ef, Di = 1.f + ei, Dg = 1.f + eg;
  float DiDg = Di*Dg;
  float r  = __builtin_amdgcn_rcpf(Df*DiDg);
  float sf = DiDg*r;                         // sigmoid(gf)
  float ig = ((eg-1.f)*Df)*r;                // sigmoid(gi)*tanh(gg)
  c = __builtin_fmaf(sf, c, ig);
  float eo = __builtin_amdgcn_exp2f(go * NL2E);
  float ec = __builtin_amdgcn_exp2f(c  * P2L2E);
  float r2 = __builtin_amdgcn_rcpf((1.f+eo)*(1.f+ec));
  h = (ec-1.f)*r2;                           // sigmoid(go)*tanh(c)
}

// ---------------- kernel 1: per-timestep batch statistics ----------------
#define RPB 512
__global__ __launch_bounds__(256) void bn_stats(const float* __restrict__ x,
                                                float* __restrict__ sums){
  __shared__ float buf[RPB*TSEQ];            // 30720 B
  const int tid = threadIdx.x;
  const float4* src = (const float4*)(x + (size_t)blockIdx.x * (RPB*TSEQ));
  float4* dst = (float4*)buf;
  #pragma unroll
  for (int i=0;i<8;i++){
    int idx = tid + i*256;
    if (idx < RPB*TSEQ/4) dst[idx] = src[idx];
  }
  __syncthreads();
  float s[TSEQ], s2[TSEQ];
  #pragma unroll
  for (int t=0;t<TSEQ;t++){ s[t]=0.f; s2[t]=0.f; }
  #pragma unroll
  for (int rr=0; rr<RPB/256; rr++){
    const float* row = buf + (tid*(RPB/256)+rr)*TSEQ;
    #pragma unroll
    for (int t=0;t<TSEQ;t++){ float v=row[t]; s[t]+=v; s2[t]=__builtin_fmaf(v,v,s2[t]); }
  }
  #pragma unroll
  for (int t=0;t<TSEQ;t++){
    #pragma unroll
    for (int off=32; off>0; off>>=1){
      s[t]  += __shfl_down(s[t],  off, 64);
      s2[t] += __shfl_down(s2[t], off, 64);
    }
  }
  __syncthreads();                           // buf reads done; reuse for partials
  const int w = tid>>6, lane = tid&63;
  if (lane==0){
    #pragma unroll
    for (int t=0;t<TSEQ;t++){ buf[w*32+t]=s[t]; buf[w*32+16+t]=s2[t]; }
  }
  __syncthreads();
  if (tid < 2*TSEQ){
    int g = (tid < TSEQ) ? tid : (tid - TSEQ + 16);
    float a = buf[g] + buf[32+g] + buf[64+g] + buf[96+g];
    atomicAdd(&sums[tid], a);
  }
}

// ---------------- kernel 2: fused BN + 2-layer LSTM + FC ----------------
__global__ __launch_bounds__(256, 3) void lstm_fused(
    const float* __restrict__ x,
    const float* __restrict__ gamma, const float* __restrict__ beta,
    const float* __restrict__ Wih0,  const float* __restrict__ Whh0,
    const float* __restrict__ bih0,  const float* __restrict__ bhh0,
    const float* __restrict__ Wih1,  const float* __restrict__ Whh1,
    const float* __restrict__ bih1,  const float* __restrict__ bhh1,
    const float* __restrict__ Wfc,   const float* __restrict__ bfc,
    const float* __restrict__ sums,  float* __restrict__ out)
{
  // double-buffered h tiles (removes WAR barrier): [buf][row stride 128B], XOR-swizzled
  __shared__ alignas(16) short h0s[2*BM*64];
  __shared__ alignas(16) short h1s[2*BM*64];
  __shared__ float xns[BM][16];
  __shared__ float scs[TSEQ], shs[TSEQ];

  const int tid  = threadIdx.x;
  const int w    = tid >> 6;        // wave id 0..3 -> owns h columns [w*16, w*16+16)
  const int lane = tid & 63;
  const int l15  = lane & 15;
  const int lg   = lane >> 4;
  const int rbase = blockIdx.x * BM;

  if (tid < TSEQ){
    const float inv = 1.f/(float)BTOT;
    float mean = sums[tid]*inv;
    float var  = sums[TSEQ+tid]*inv - mean*mean;
    float sc = gamma[tid] * rsqrtf(var + 1e-5f);
    scs[tid] = sc;
    shs[tid] = beta[tid] - mean*sc;
  }
  #pragma unroll
  for (int i=0;i<8;i++){ h0s[tid + i*256] = 0; h1s[tid + i*256] = 0; }  // zero buffer 0
  __syncthreads();
  for (int i = tid; i < BM*TSEQ; i += 256){
    int r = i/TSEQ, t = i - r*TSEQ;
    xns[r][t] = x[(rbase+r)*TSEQ + t] * scs[t] + shs[t];
  }

  // ---- per-lane constants & weight B-fragments (registers, bf16) ----
  float wx0[4], bs0[4], bs1[4];
  bf16x8 wB0[2][4], wB1[4][4], wFC[2];
  #pragma unroll
  for (int n=0;n<4;n++){
    int g = n*64 + w*16 + l15;          // gate column (i/f/g/o block n)
    wx0[n] = Wih0[g];
    bs0[n] = bih0[g] + bhh0[g];
    bs1[n] = bih1[g] + bhh1[g];
    #pragma unroll
    for (int kk=0;kk<2;kk++){
      const float* p = Whh0 + g*64 + kk*32 + lg*8;
      #pragma unroll
      for (int e=0;e<8;e++) wB0[kk][n][e] = f2bf(p[e]);
    }
    #pragma unroll
    for (int kk=0;kk<4;kk++){           // combined K=128: [W_ih1 | W_hh1]
      const float* bsrc = (kk<2) ? Wih1 : Whh1;
      const float* p = bsrc + g*64 + (kk&1)*32 + lg*8;
      #pragma unroll
      for (int e=0;e<8;e++) wB1[kk][n][e] = f2bf(p[e]);
    }
  }
  float fcb;
  {
    int o = w*16 + l15;
    fcb = bfc[o];
    #pragma unroll
    for (int kk=0;kk<2;kk++){
      const float* p = Wfc + o*64 + kk*32 + lg*8;
      #pragma unroll
      for (int e=0;e<8;e++) wFC[kk][e] = f2bf(p[e]);
    }
  }

  // cell state in MFMA C-layout: row = m*16 + lg*4 + r, col = w*16 + l15
  f32x4 c0[2], c1[2];
  #pragma unroll
  for (int m=0;m<2;m++){
    c0[m] = (f32x4){0.f,0.f,0.f,0.f};
    c1[m] = (f32x4){0.f,0.f,0.f,0.f};
  }

  __syncthreads();

  #pragma unroll 1
  for (int t=0; t<TSEQ; t++){
    const int pr = (t&1)*2048, pw = ((t&1)^1)*2048;   // read/write buffer bases
    f32x4 acc[2][4];
    // ----- layer 0: gates = bias + xn*W_ih0 (rank-1, I=1) + h0 @ Whh0^T -----
    #pragma unroll
    for (int m=0;m<2;m++){
      #pragma unroll
      for (int r=0;r<4;r++){
        float xv = xns[m*16 + lg*4 + r][t];
        #pragma unroll
        for (int n=0;n<4;n++) acc[m][n][r] = __builtin_fmaf(xv, wx0[n], bs0[n]);
      }
    }
    #pragma unroll
    for (int kk=0;kk<2;kk++){
      #pragma unroll
      for (int m=0;m<2;m++){
        int row = m*16 + l15;
        int off = ((row*128 + kk*64 + lg*16) ^ ((row&7)<<4));
        bf16x8 a = *(const bf16x8*)((const char*)(h0s+pr) + off);
        #pragma unroll
        for (int n=0;n<4;n++)
          acc[m][n] = __builtin_amdgcn_mfma_f32_16x16x32_bf16(a, wB0[kk][n], acc[m][n], 0,0,0);
      }
    }
    #pragma unroll
    for (int m=0;m<2;m++){
      #pragma unroll
      for (int r=0;r<4;r++){
        float c = c0[m][r], h;
        lstm_act(acc[m][0][r], acc[m][1][r], acc[m][2][r], acc[m][3][r], c, h);
        c0[m][r] = c;
        int row = m*16 + lg*4 + r;
        int off = ((row*128 + (w*16 + l15)*2) ^ ((row&7)<<4));
        *(short*)((char*)(h0s+pw) + off) = f2bf(h);
      }
    }
    __syncthreads();                    // B_a: h0(t) visible in pw

    // ----- layer 1: gates = bias + [h0(t)|h1(t-1)] @ [Wih1|Whh1]^T -----
    #pragma unroll
    for (int m=0;m<2;m++)
      #pragma unroll
      for (int n=0;n<4;n++)
        #pragma unroll
        for (int r=0;r<4;r++)
          acc[m][n][r] = bs1[n];
    #pragma unroll
    for (int kk=0;kk<4;kk++){
      const short* asrc = (kk<2) ? (h0s+pw) : (h1s+pr);
      #pragma unroll
      for (int m=0;m<2;m++){
        int row = m*16 + l15;
        int off = ((row*128 + (kk&1)*64 + lg*16) ^ ((row&7)<<4));
        bf16x8 a = *(const bf16x8*)((const char*)asrc + off);
        #pragma unroll
        for (int n=0;n<4;n++)
          acc[m][n] = __builtin_amdgcn_mfma_f32_16x16x32_bf16(a, wB1[kk][n], acc[m][n], 0,0,0);
      }
    }
    #pragma unroll
    for (int m=0;m<2;m++){
      #pragma unroll
      for (int r=0;r<4;r++){
        float c = c1[m][r], h;
        lstm_act(acc[m][0][r], acc[m][1][r], acc[m][2][r], acc[m][3][r], c, h);
        c1[m][r] = c;
        int row = m*16 + lg*4 + r;
        int off = ((row*128 + (w*16 + l15)*2) ^ ((row&7)<<4));
        *(short*)((char*)(h1s+pw) + off) = f2bf(h);
      }
    }
    __syncthreads();                    // B_b: h1(t) visible; WAR safe via dbuf
  }

  // ----- FC: out = relu(h1 @ Wfc^T + bfc) ----- (final h1 in buffer TSEQ&1)
  const short* h1f = h1s + (TSEQ&1)*2048;
  f32x4 accF[2];
  #pragma unroll
  for (int m=0;m<2;m++)
    #pragma unroll
    for (int r=0;r<4;r++) accF[m][r] = fcb;
  #pragma unroll
  for (int kk=0;kk<2;kk++){
    #pragma unroll
    for (int m=0;m<2;m++){
      int row = m*16 + l15;
      int off = ((row*128 + kk*64 + lg*16) ^ ((row&7)<<4));
      bf16x8 a = *(const bf16x8*)((const char*)h1f + off);
      accF[m] = __builtin_amdgcn_mfma_f32_16x16x32_bf16(a, wFC[kk], accF[m], 0,0,0);
    }
  }
  #pragma unroll
  for (int m=0;m<2;m++){
    #pragma unroll
    for (int r=0;r<4;r++){
      float v = accF[m][r];
      v = v > 0.f ? v : 0.f;
      out[(rbase + m*16 + lg*4 + r)*64 + w*16 + l15] = v;
    }
  }
}

extern "C" void kernel_launch(void* const* d_in, const int* in_sizes, int n_in,
                              void* d_out, int out_size, void* d_ws, size_t ws_size,
                              hipStream_t stream) {
  const float* x     = (const float*)d_in[0];
  const float* gamma = (const float*)d_in[1];
  const float* beta  = (const float*)d_in[2];
  const float* Wih0  = (const float*)d_in[3];
  const float* Whh0  = (const float*)d_in[4];
  const float* bih0  = (const float*)d_in[5];
  const float* bhh0  = (const float*)d_in[6];
  const float* Wih1  = (const float*)d_in[7];
  const float* Whh1  = (const float*)d_in[8];
  const float* bih1  = (const float*)d_in[9];
  const float* bhh1  = (const float*)d_in[10];
  const float* Wfc   = (const float*)d_in[11];
  const float* bfc   = (const float*)d_in[12];
  float* sums = (float*)d_ws;
  float* out  = (float*)d_out;

  hipMemsetAsync(d_ws, 0, 2*TSEQ*sizeof(float), stream);
  bn_stats<<<dim3(BTOT/RPB), dim3(256), 0, stream>>>(x, sums);
  lstm_fused<<<dim3(BTOT/BM), dim3(256), 0, stream>>>(
      x, gamma, beta, Wih0, Whh0, bih0, bhh0,
      Wih1, Whh1, bih1, bhh1, Wfc, bfc, sums, out);
}

// Round 3
// 378.810 us; speedup vs baseline: 1.9854x; 1.9854x over previous
//
#include <hip/hip_runtime.h>

#define BTOT 131072
#define TSEQ 15
#define BM   32

typedef __attribute__((ext_vector_type(8))) short bf16x8;
typedef __attribute__((ext_vector_type(4))) float f32x4;

__device__ __forceinline__ short f2bf(float f){
  union{float f; unsigned u;} v; v.f=f;
  unsigned r = v.u + 0x7FFFu + ((v.u>>16)&1u);
  return (short)(r>>16);
}

// Shared-rcp LSTM activation: 7 trans ops (5 exp2 + 2 rcp) instead of 10.
//  sf = DiDg/(Df*Di*Dg), si*tanh(g) = (eg-1)*Df/(Df*Di*Dg), h = (ec-1)/(Do*Dc)
__device__ __forceinline__ void lstm_act(float gi, float gf, float gg, float go,
                                         float& c, float& h){
  const float NL2E = -1.4426950408889634f;   // -log2(e)
  const float P2L2E = 2.8853900817779268f;   // 2*log2(e)
  float ef = __builtin_amdgcn_exp2f(gf * NL2E);
  float ei = __builtin_amdgcn_exp2f(gi * NL2E);
  float eg = __builtin_amdgcn_exp2f(gg * P2L2E);
  float Df = 1.f + ef, Di = 1.f + ei, Dg = 1.f + eg;
  float DiDg = Di*Dg;
  float r  = __builtin_amdgcn_rcpf(Df*DiDg);
  float sf = DiDg*r;                         // sigmoid(gf)
  float ig = ((eg-1.f)*Df)*r;                // sigmoid(gi)*tanh(gg)
  c = __builtin_fmaf(sf, c, ig);
  float eo = __builtin_amdgcn_exp2f(go * NL2E);
  float ec = __builtin_amdgcn_exp2f(c  * P2L2E);
  float r2 = __builtin_amdgcn_rcpf((1.f+eo)*(1.f+ec));
  h = (ec-1.f)*r2;                           // sigmoid(go)*tanh(c)
}

// ---------------- kernel 1: per-timestep batch statistics ----------------
#define RPB 512
__global__ __launch_bounds__(256) void bn_stats(const float* __restrict__ x,
                                                float* __restrict__ sums){
  __shared__ float buf[RPB*TSEQ];            // 30720 B
  const int tid = threadIdx.x;
  const float4* src = (const float4*)(x + (size_t)blockIdx.x * (RPB*TSEQ));
  float4* dst = (float4*)buf;
  #pragma unroll
  for (int i=0;i<8;i++){
    int idx = tid + i*256;
    if (idx < RPB*TSEQ/4) dst[idx] = src[idx];
  }
  __syncthreads();
  float s[TSEQ], s2[TSEQ];
  #pragma unroll
  for (int t=0;t<TSEQ;t++){ s[t]=0.f; s2[t]=0.f; }
  #pragma unroll
  for (int rr=0; rr<RPB/256; rr++){
    const float* row = buf + (tid*(RPB/256)+rr)*TSEQ;
    #pragma unroll
    for (int t=0;t<TSEQ;t++){ float v=row[t]; s[t]+=v; s2[t]=__builtin_fmaf(v,v,s2[t]); }
  }
  #pragma unroll
  for (int t=0;t<TSEQ;t++){
    #pragma unroll
    for (int off=32; off>0; off>>=1){
      s[t]  += __shfl_down(s[t],  off, 64);
      s2[t] += __shfl_down(s2[t], off, 64);
    }
  }
  __syncthreads();                           // buf reads done; reuse for partials
  const int w = tid>>6, lane = tid&63;
  if (lane==0){
    #pragma unroll
    for (int t=0;t<TSEQ;t++){ buf[w*32+t]=s[t]; buf[w*32+16+t]=s2[t]; }
  }
  __syncthreads();
  if (tid < 2*TSEQ){
    int g = (tid < TSEQ) ? tid : (tid - TSEQ + 16);
    float a = buf[g] + buf[32+g] + buf[64+g] + buf[96+g];
    atomicAdd(&sums[tid], a);
  }
}

// ---------------- kernel 2: fused BN + 2-layer LSTM + FC ----------------
// NOTE: 2nd launch_bounds arg > 2 makes the allocator spill the resident
// weight fragments (round-2: 84 VGPR + 2.6 GB scratch traffic). Keep at 2.
__global__ __launch_bounds__(256, 2) void lstm_fused(
    const float* __restrict__ x,
    const float* __restrict__ gamma, const float* __restrict__ beta,
    const float* __restrict__ Wih0,  const float* __restrict__ Whh0,
    const float* __restrict__ bih0,  const float* __restrict__ bhh0,
    const float* __restrict__ Wih1,  const float* __restrict__ Whh1,
    const float* __restrict__ bih1,  const float* __restrict__ bhh1,
    const float* __restrict__ Wfc,   const float* __restrict__ bfc,
    const float* __restrict__ sums,  float* __restrict__ out)
{
  // double-buffered h tiles (2 barriers/step): [buf][row stride 128B], XOR-swizzled
  __shared__ alignas(16) short h0s[2*BM*64];
  __shared__ alignas(16) short h1s[2*BM*64];
  __shared__ float xns[BM][17];              // stride 17 floats: kills 4-way bank conflict
  __shared__ float scs[TSEQ], shs[TSEQ];

  const int tid  = threadIdx.x;
  const int w    = tid >> 6;        // wave id 0..3 -> owns h columns [w*16, w*16+16)
  const int lane = tid & 63;
  const int l15  = lane & 15;
  const int lg   = lane >> 4;
  const int rbase = blockIdx.x * BM;

  if (tid < TSEQ){
    const float inv = 1.f/(float)BTOT;
    float mean = sums[tid]*inv;
    float var  = sums[TSEQ+tid]*inv - mean*mean;
    float sc = gamma[tid] * rsqrtf(var + 1e-5f);
    scs[tid] = sc;
    shs[tid] = beta[tid] - mean*sc;
  }
  #pragma unroll
  for (int i=0;i<8;i++){ h0s[tid + i*256] = 0; h1s[tid + i*256] = 0; }  // zero buffer 0
  __syncthreads();
  for (int i = tid; i < BM*TSEQ; i += 256){
    int r = i/TSEQ, t = i - r*TSEQ;
    xns[r][t] = x[(rbase+r)*TSEQ + t] * scs[t] + shs[t];
  }

  // ---- per-lane constants & weight B-fragments (registers, bf16) ----
  float wx0[4], bs0[4], bs1[4];
  bf16x8 wB0[2][4], wB1[4][4], wFC[2];
  #pragma unroll
  for (int n=0;n<4;n++){
    int g = n*64 + w*16 + l15;          // gate column (i/f/g/o block n)
    wx0[n] = Wih0[g];
    bs0[n] = bih0[g] + bhh0[g];
    bs1[n] = bih1[g] + bhh1[g];
    #pragma unroll
    for (int kk=0;kk<2;kk++){
      const float* p = Whh0 + g*64 + kk*32 + lg*8;
      #pragma unroll
      for (int e=0;e<8;e++) wB0[kk][n][e] = f2bf(p[e]);
    }
    #pragma unroll
    for (int kk=0;kk<4;kk++){           // combined K=128: [W_ih1 | W_hh1]
      const float* bsrc = (kk<2) ? Wih1 : Whh1;
      const float* p = bsrc + g*64 + (kk&1)*32 + lg*8;
      #pragma unroll
      for (int e=0;e<8;e++) wB1[kk][n][e] = f2bf(p[e]);
    }
  }
  float fcb;
  {
    int o = w*16 + l15;
    fcb = bfc[o];
    #pragma unroll
    for (int kk=0;kk<2;kk++){
      const float* p = Wfc + o*64 + kk*32 + lg*8;
      #pragma unroll
      for (int e=0;e<8;e++) wFC[kk][e] = f2bf(p[e]);
    }
  }

  // cell state in MFMA C-layout: row = m*16 + lg*4 + r, col = w*16 + l15
  f32x4 c0[2], c1[2];
  #pragma unroll
  for (int m=0;m<2;m++){
    c0[m] = (f32x4){0.f,0.f,0.f,0.f};
    c1[m] = (f32x4){0.f,0.f,0.f,0.f};
  }

  __syncthreads();

  #pragma unroll 2
  for (int t=0; t<TSEQ; t++){
    const int pr = (t&1)*2048, pw = ((t&1)^1)*2048;   // read/write buffer bases
    f32x4 acc[2][4];
    // ----- layer 0: gates = bias + xn*W_ih0 (rank-1, I=1) + h0 @ Whh0^T -----
    #pragma unroll
    for (int m=0;m<2;m++){
      #pragma unroll
      for (int r=0;r<4;r++){
        float xv = xns[m*16 + lg*4 + r][t];
        #pragma unroll
        for (int n=0;n<4;n++) acc[m][n][r] = __builtin_fmaf(xv, wx0[n], bs0[n]);
      }
    }
    #pragma unroll
    for (int kk=0;kk<2;kk++){
      #pragma unroll
      for (int m=0;m<2;m++){
        int row = m*16 + l15;
        int off = ((row*128 + kk*64 + lg*16) ^ ((row&7)<<4));
        bf16x8 a = *(const bf16x8*)((const char*)(h0s+pr) + off);
        #pragma unroll
        for (int n=0;n<4;n++)
          acc[m][n] = __builtin_amdgcn_mfma_f32_16x16x32_bf16(a, wB0[kk][n], acc[m][n], 0,0,0);
      }
    }
    #pragma unroll
    for (int m=0;m<2;m++){
      #pragma unroll
      for (int r=0;r<4;r++){
        float c = c0[m][r], h;
        lstm_act(acc[m][0][r], acc[m][1][r], acc[m][2][r], acc[m][3][r], c, h);
        c0[m][r] = c;
        int row = m*16 + lg*4 + r;
        int off = ((row*128 + (w*16 + l15)*2) ^ ((row&7)<<4));
        *(short*)((char*)(h0s+pw) + off) = f2bf(h);
      }
    }
    __syncthreads();                    // B_a: h0(t) visible in pw

    // ----- layer 1: gates = bias + [h0(t)|h1(t-1)] @ [Wih1|Whh1]^T -----
    #pragma unroll
    for (int m=0;m<2;m++)
      #pragma unroll
      for (int n=0;n<4;n++)
        #pragma unroll
        for (int r=0;r<4;r++)
          acc[m][n][r] = bs1[n];
    #pragma unroll
    for (int kk=0;kk<4;kk++){
      const short* asrc = (kk<2) ? (h0s+pw) : (h1s+pr);
      #pragma unroll
      for (int m=0;m<2;m++){
        int row = m*16 + l15;
        int off = ((row*128 + (kk&1)*64 + lg*16) ^ ((row&7)<<4));
        bf16x8 a = *(const bf16x8*)((const char*)asrc + off);
        #pragma unroll
        for (int n=0;n<4;n++)
          acc[m][n] = __builtin_amdgcn_mfma_f32_16x16x32_bf16(a, wB1[kk][n], acc[m][n], 0,0,0);
      }
    }
    #pragma unroll
    for (int m=0;m<2;m++){
      #pragma unroll
      for (int r=0;r<4;r++){
        float c = c1[m][r], h;
        lstm_act(acc[m][0][r], acc[m][1][r], acc[m][2][r], acc[m][3][r], c, h);
        c1[m][r] = c;
        int row = m*16 + lg*4 + r;
        int off = ((row*128 + (w*16 + l15)*2) ^ ((row&7)<<4));
        *(short*)((char*)(h1s+pw) + off) = f2bf(h);
      }
    }
    __syncthreads();                    // B_b: h1(t) visible; WAR safe via dbuf
  }

  // ----- FC: out = relu(h1 @ Wfc^T + bfc) ----- (final h1 in buffer TSEQ&1)
  const short* h1f = h1s + (TSEQ&1)*2048;
  f32x4 accF[2];
  #pragma unroll
  for (int m=0;m<2;m++)
    #pragma unroll
    for (int r=0;r<4;r++) accF[m][r] = fcb;
  #pragma unroll
  for (int kk=0;kk<2;kk++){
    #pragma unroll
    for (int m=0;m<2;m++){
      int row = m*16 + l15;
      int off = ((row*128 + kk*64 + lg*16) ^ ((row&7)<<4));
      bf16x8 a = *(const bf16x8*)((const char*)h1f + off);
      accF[m] = __builtin_amdgcn_mfma_f32_16x16x32_bf16(a, wFC[kk], accF[m], 0,0,0);
    }
  }
  #pragma unroll
  for (int m=0;m<2;m++){
    #pragma unroll
    for (int r=0;r<4;r++){
      float v = accF[m][r];
      v = v > 0.f ? v : 0.f;
      out[(rbase + m*16 + lg*4 + r)*64 + w*16 + l15] = v;
    }
  }
}

extern "C" void kernel_launch(void* const* d_in, const int* in_sizes, int n_in,
                              void* d_out, int out_size, void* d_ws, size_t ws_size,
                              hipStream_t stream) {
  const float* x     = (const float*)d_in[0];
  const float* gamma = (const float*)d_in[1];
  const float* beta  = (const float*)d_in[2];
  const float* Wih0  = (const float*)d_in[3];
  const float* Whh0  = (const float*)d_in[4];
  const float* bih0  = (const float*)d_in[5];
  const float* bhh0  = (const float*)d_in[6];
  const float* Wih1  = (const float*)d_in[7];
  const float* Whh1  = (const float*)d_in[8];
  const float* bih1  = (const float*)d_in[9];
  const float* bhh1  = (const float*)d_in[10];
  const float* Wfc   = (const float*)d_in[11];
  const float* bfc   = (const float*)d_in[12];
  float* sums = (float*)d_ws;
  float* out  = (float*)d_out;

  hipMemsetAsync(d_ws, 0, 2*TSEQ*sizeof(float), stream);
  bn_stats<<<dim3(BTOT/RPB), dim3(256), 0, stream>>>(x, sums);
  lstm_fused<<<dim3(BTOT/BM), dim3(256), 0, stream>>>(
      x, gamma, beta, Wih0, Whh0, bih0, bhh0,
      Wih1, Whh1, bih1, bhh1, Wfc, bfc, sums, out);
}